// Round 11
// baseline (262.330 us; speedup 1.0000x reference)
//
#include <hip/hip_runtime.h>

typedef short bf8_t __attribute__((ext_vector_type(8)));   // 8 bf16 in 4 VGPRs
typedef float f32x4 __attribute__((ext_vector_type(4)));

__device__ inline unsigned short f2bf(float f) {        // RNE f32 -> bf16
    unsigned u = __float_as_uint(f);
    return (unsigned short)((u + 0x7fff + ((u >> 16) & 1)) >> 16);
}

// ---------------- CSR construction ----------------

__global__ void deg_kernel(const int* __restrict__ dst, int* __restrict__ deg,
                           int* __restrict__ rank, int E) {
    int e = blockIdx.x * 256 + threadIdx.x;
    if (e < E) rank[e] = atomicAdd(&deg[dst[e]], 1);
}

// block sums of (deg+1) for rowptr scan; also emits dinv = rsqrt(deg+1)
__global__ void scan_blocksum(const int* __restrict__ deg, int* __restrict__ bsum,
                              float* __restrict__ dinv, int n) {
    int i = blockIdx.x * 256 + threadIdx.x;
    int d = (i < n) ? (deg[i] + 1) : 0;
    if (i < n) dinv[i] = rsqrtf((float)d);
    int v = d;
    for (int off = 32; off > 0; off >>= 1) v += __shfl_down(v, off, 64);
    __shared__ int ws[4];
    if ((threadIdx.x & 63) == 0) ws[threadIdx.x >> 6] = v;
    __syncthreads();
    if (threadIdx.x == 0) bsum[blockIdx.x] = ws[0] + ws[1] + ws[2] + ws[3];
}

__global__ void scan_offsets(const int* __restrict__ bsum, int* __restrict__ boff, int nblk) {
    __shared__ int buf[256];
    int tid = threadIdx.x;
    int v = (tid < nblk) ? bsum[tid] : 0;
    buf[tid] = v;
    __syncthreads();
    for (int off = 1; off < 256; off <<= 1) {
        int t = (tid >= off) ? buf[tid - off] : 0;
        __syncthreads();
        buf[tid] += t;
        __syncthreads();
    }
    if (tid < nblk) boff[tid] = buf[tid] - v;   // exclusive
}

__global__ void scan_rowptr(const int* __restrict__ deg, const int* __restrict__ boff,
                            int* __restrict__ row_ptr, int n) {
    __shared__ int buf[256];
    int tid = threadIdx.x;
    int i = blockIdx.x * 256 + tid;
    int v = (i < n) ? (deg[i] + 1) : 0;
    buf[tid] = v;
    __syncthreads();
    for (int off = 1; off < 256; off <<= 1) {
        int t = (tid >= off) ? buf[tid - off] : 0;
        __syncthreads();
        buf[tid] += t;
        __syncthreads();
    }
    int excl = buf[tid] - v + boff[blockIdx.x];
    if (i < n) row_ptr[i] = excl;
    if (i == n - 1) row_ptr[n] = excl + v;
}

// Atomic-free fill: pos = row_ptr[dst] + 1 + rank (self-loop deterministically at slot 0).
__global__ void fill_kernel(const int* __restrict__ src, const int* __restrict__ dst,
                            const int* __restrict__ rank,
                            const int* __restrict__ row_ptr,
                            int* __restrict__ csr_src, int E, int n) {
    int e = blockIdx.x * 256 + threadIdx.x;
    if (e < E) {
        int s = src[e], d = dst[e];
        int pos = row_ptr[d] + 1 + rank[e];
        __builtin_nontemporal_store(s, &csr_src[pos]);
    } else if (e < E + n) {
        int s = e - E;
        __builtin_nontemporal_store(s, &csr_src[row_ptr[s]]);
    }
}

// Convert x (N*64 fp32) to bf16 once.
__global__ void x2bf_kernel(const float* __restrict__ x, unsigned* __restrict__ x16,
                            int total8) {   // total8 = N*64/8
    int i = blockIdx.x * 256 + threadIdx.x;
    if (i >= total8) return;
    const float4* x4 = (const float4*)x;
    float4 a = x4[i * 2], b = x4[i * 2 + 1];
    uint4 o;
    o.x = (unsigned)f2bf(a.x) | ((unsigned)f2bf(a.y) << 16);
    o.y = (unsigned)f2bf(a.z) | ((unsigned)f2bf(a.w) << 16);
    o.z = (unsigned)f2bf(b.x) | ((unsigned)f2bf(b.y) << 16);
    o.w = (unsigned)f2bf(b.z) | ((unsigned)f2bf(b.w) << 16);
    ((uint4*)x16)[i] = o;
}

// All three W [K x 128] fp32 -> W^T [128 x K] bf16, one launch (40960 elems).
__global__ void wt_all(const float* __restrict__ W1, const float* __restrict__ W2,
                       const float* __restrict__ W3,
                       unsigned short* __restrict__ Wt1, unsigned short* __restrict__ Wt2,
                       unsigned short* __restrict__ Wt3) {
    int i = blockIdx.x * 256 + threadIdx.x;
    if (i < 8192) {                       // W1: K=64
        int nn = i / 64, k = i - nn * 64;
        Wt1[i] = f2bf(W1[k * 128 + nn]);
    } else if (i < 24576) {               // W2: K=128
        int j = i - 8192;
        int nn = j / 128, k = j - nn * 128;
        Wt2[j] = f2bf(W2[k * 128 + nn]);
    } else if (i < 40960) {               // W3: K=128
        int j = i - 24576;
        int nn = j / 128, k = j - nn * 128;
        Wt3[j] = f2bf(W3[k * 128 + nn]);
    }
}

// ---------------- Fused aggregate + MFMA GEMM ----------------
// out[node] = (dinv[node] * sum_s dinv[s]*in[s]) @ W^T + bias, optional ReLU.
// Block = 16 nodes, 4 waves. Wave w aggregates LDS rows w*4..w*4+3 (bf16, XOR-swizzled),
// then computes output cols w*32..w*32+31 via 16x16x32 bf16 MFMA.
// Gather: 4-deep unroll -> 16 edge-rows in flight per wave (Little's law: bf16 rows
// are 256 B, need 2x the edges of the fp32 version for the same outstanding bytes).

__device__ inline void bf8_fma(uint4 a, float w, float* acc) {
#pragma unroll
    for (int j = 0; j < 4; ++j) {
        unsigned u = ((const unsigned*)&a)[j];
        acc[2 * j]     = fmaf(w, __uint_as_float(u << 16), acc[2 * j]);
        acc[2 * j + 1] = fmaf(w, __uint_as_float(u & 0xffff0000u), acc[2 * j + 1]);
    }
}

__device__ inline uint4 pack_bf8(const float* v, float dn) {
    uint4 o;
    o.x = (unsigned)f2bf(v[0] * dn) | ((unsigned)f2bf(v[1] * dn) << 16);
    o.y = (unsigned)f2bf(v[2] * dn) | ((unsigned)f2bf(v[3] * dn) << 16);
    o.z = (unsigned)f2bf(v[4] * dn) | ((unsigned)f2bf(v[5] * dn) << 16);
    o.w = (unsigned)f2bf(v[6] * dn) | ((unsigned)f2bf(v[7] * dn) << 16);
    return o;
}

template<int K, bool RELU, bool BF16OUT>
__global__ __launch_bounds__(256) void agg_gemm(
        const unsigned short* __restrict__ in, const unsigned short* __restrict__ Wt16,
        const float* __restrict__ bias, void* __restrict__ outp,
        const int* __restrict__ row_ptr, const int* __restrict__ csr_src,
        const float* __restrict__ dinv, int n) {
    constexpr int KS = K / 32;
    __shared__ unsigned short As[16 * K];
    int w = threadIdx.x >> 6, lane = threadIdx.x & 63;
    int base = blockIdx.x * 16;
    int lr = lane & 15, lk = lane >> 4;

    // Preload W frags (cols w*32..+31) before gather for latency overlap.
    bf8_t B[2][KS];
#pragma unroll
    for (int f = 0; f < 2; ++f) {
        int col = w * 32 + f * 16 + lr;
#pragma unroll
        for (int ks = 0; ks < KS; ++ks)
            B[f][ks] = *reinterpret_cast<const bf8_t*>(&Wt16[(size_t)col * K + ks * 32 + lk * 8]);
    }

    const uint4* in4 = (const uint4*)in;
    for (int nd = 0; nd < 4; ++nd) {
        int row = w * 4 + nd;
        int node = base + row;
        float acc[8] = {0.f, 0.f, 0.f, 0.f, 0.f, 0.f, 0.f, 0.f};
        if (node < n) {
            int beg = row_ptr[node], end = row_ptr[node + 1];
            if (K == 128) {          // row = 16 uint4; 16 lanes/edge, 4 groups
                int col = lane & 15;
                int i = beg + (lane >> 4);
                for (; i + 12 < end; i += 16) {     // 4-deep: 16 edges in flight/wave
                    int s0 = csr_src[i],     s1 = csr_src[i + 4];
                    int s2 = csr_src[i + 8], s3 = csr_src[i + 12];
                    uint4 a0 = in4[(size_t)s0 * 16 + col];
                    uint4 a1 = in4[(size_t)s1 * 16 + col];
                    uint4 a2 = in4[(size_t)s2 * 16 + col];
                    uint4 a3 = in4[(size_t)s3 * 16 + col];
                    float w0 = dinv[s0], w1 = dinv[s1], w2 = dinv[s2], w3 = dinv[s3];
                    bf8_fma(a0, w0, acc); bf8_fma(a1, w1, acc);
                    bf8_fma(a2, w2, acc); bf8_fma(a3, w3, acc);
                }
                for (; i + 4 < end; i += 8) {
                    int s0 = csr_src[i], s1 = csr_src[i + 4];
                    uint4 a = in4[(size_t)s0 * 16 + col];
                    uint4 b = in4[(size_t)s1 * 16 + col];
                    float w0 = dinv[s0], w1 = dinv[s1];
                    bf8_fma(a, w0, acc);
                    bf8_fma(b, w1, acc);
                }
                if (i < end) { int s = csr_src[i]; bf8_fma(in4[(size_t)s * 16 + col], dinv[s], acc); }
#pragma unroll
                for (int j = 0; j < 8; ++j) {
                    acc[j] += __shfl_xor(acc[j], 16, 64);
                    acc[j] += __shfl_xor(acc[j], 32, 64);
                }
            } else {                 // K==64: row = 8 uint4; 8 lanes/edge, 8 groups
                int col = lane & 7;
                int i = beg + (lane >> 3);
                for (; i + 24 < end; i += 32) {     // 4-deep: 32 edges in flight/wave
                    int s0 = csr_src[i],      s1 = csr_src[i + 8];
                    int s2 = csr_src[i + 16], s3 = csr_src[i + 24];
                    uint4 a0 = in4[(size_t)s0 * 8 + col];
                    uint4 a1 = in4[(size_t)s1 * 8 + col];
                    uint4 a2 = in4[(size_t)s2 * 8 + col];
                    uint4 a3 = in4[(size_t)s3 * 8 + col];
                    float w0 = dinv[s0], w1 = dinv[s1], w2 = dinv[s2], w3 = dinv[s3];
                    bf8_fma(a0, w0, acc); bf8_fma(a1, w1, acc);
                    bf8_fma(a2, w2, acc); bf8_fma(a3, w3, acc);
                }
                for (; i + 8 < end; i += 16) {
                    int s0 = csr_src[i], s1 = csr_src[i + 8];
                    uint4 a = in4[(size_t)s0 * 8 + col];
                    uint4 b = in4[(size_t)s1 * 8 + col];
                    float w0 = dinv[s0], w1 = dinv[s1];
                    bf8_fma(a, w0, acc);
                    bf8_fma(b, w1, acc);
                }
                if (i < end) { int s = csr_src[i]; bf8_fma(in4[(size_t)s * 8 + col], dinv[s], acc); }
#pragma unroll
                for (int j = 0; j < 8; ++j) {
                    acc[j] += __shfl_xor(acc[j], 8, 64);
                    acc[j] += __shfl_xor(acc[j], 16, 64);
                    acc[j] += __shfl_xor(acc[j], 32, 64);
                }
            }
        }
        // LDS write, swizzled: 16-way bank conflict on read otherwise (row stride % 128B == 0)
        if (lane < K / 8) {
            float dn = (node < n) ? dinv[node] : 0.f;
            uint4 o = pack_bf8(acc, dn);
            int off = row * K + ((lane * 8) ^ ((row & 7) << 3));
            *(uint4*)&As[off] = o;
        }
    }
    __syncthreads();

    f32x4 pacc[2] = {};
#pragma unroll
    for (int ks = 0; ks < KS; ++ks) {
        int off = lr * K + (((ks * 32) + lk * 8) ^ ((lr & 7) << 3));
        bf8_t a = *reinterpret_cast<const bf8_t*>(&As[off]);
#pragma unroll
        for (int f = 0; f < 2; ++f)
            pacc[f] = __builtin_amdgcn_mfma_f32_16x16x32_bf16(B[f][ks], a, pacc[f], 0, 0, 0);
    }

    int orow = base + lr;
    if (orow < n) {
#pragma unroll
        for (int f = 0; f < 2; ++f) {
            int c0 = w * 32 + f * 16 + lk * 4;
            float4 bv = *(const float4*)&bias[c0];
            float v0 = pacc[f][0] + bv.x, v1 = pacc[f][1] + bv.y;
            float v2 = pacc[f][2] + bv.z, v3 = pacc[f][3] + bv.w;
            if (RELU) {
                v0 = fmaxf(v0, 0.f); v1 = fmaxf(v1, 0.f);
                v2 = fmaxf(v2, 0.f); v3 = fmaxf(v3, 0.f);
            }
            if (BF16OUT) {
                uint2 o;
                o.x = (unsigned)f2bf(v0) | ((unsigned)f2bf(v1) << 16);
                o.y = (unsigned)f2bf(v2) | ((unsigned)f2bf(v3) << 16);
                *(uint2*)&((unsigned short*)outp)[(size_t)orow * 128 + c0] = o;
            } else {
                *(float4*)&((float*)outp)[(size_t)orow * 128 + c0] = make_float4(v0, v1, v2, v3);
            }
        }
    }
}

// ---------------- Pooling + head ----------------

__global__ void gstart_bs(const int* __restrict__ batch, int* __restrict__ gstart,
                          int n, int G) {
    int g = blockIdx.x * blockDim.x + threadIdx.x;
    if (g > G) return;
    int lo = 0, hi = n;
    while (lo < hi) {
        int mid = (lo + hi) >> 1;
        if (batch[mid] < g) lo = mid + 1; else hi = mid;
    }
    gstart[g] = lo;
}

#define PSPLIT 16
__global__ __launch_bounds__(256) void pool_part(
        const float* __restrict__ h, const int* __restrict__ gstart,
        float* __restrict__ part) {
    int g = blockIdx.x >> 4, sp = blockIdx.x & (PSPLIT - 1);
    int tid = threadIdx.x;
    int c = tid & 127, rs = tid >> 7;
    int beg = gstart[g], end = gstart[g + 1];
    int len = end - beg;
    int chunk = (len + PSPLIT - 1) >> 4;
    int r0 = beg + sp * chunk;
    int r1 = min(r0 + chunk, end);
    float acc = 0.f;
    for (int r = r0 + rs; r < r1; r += 2)
        acc += h[(size_t)r * 128 + c];
    __shared__ float buf[256];
    buf[tid] = acc;
    __syncthreads();
    if (rs == 0)
        part[(size_t)blockIdx.x * 128 + c] = buf[c] + buf[c + 128];
}

__global__ __launch_bounds__(128) void pool_final(
        const float* __restrict__ part, const int* __restrict__ gstart,
        float* __restrict__ gout) {
    int g = blockIdx.x;
    int c = threadIdx.x;
    float acc = 0.f;
#pragma unroll
    for (int sp = 0; sp < PSPLIT; ++sp)
        acc += part[((size_t)g * PSPLIT + sp) * 128 + c];
    int cnt = gstart[g + 1] - gstart[g];
    gout[g * 128 + c] = acc / fmaxf((float)cnt, 1.f);
}

__global__ void head_kernel(const float* __restrict__ g, const float* __restrict__ Wh,
                            const float* __restrict__ bh, float* __restrict__ out, int G) {
    int tid = blockIdx.x * blockDim.x + threadIdx.x;
    if (tid >= G * 8) return;
    int gi = tid >> 3, o = tid & 7;
    float acc = bh[o];
    for (int k = 0; k < 128; ++k)
        acc = fmaf(g[gi * 128 + k], Wh[k * 8 + o], acc);
    out[tid] = acc;
}

// ---------------- Launch ----------------

extern "C" void kernel_launch(void* const* d_in, const int* in_sizes, int n_in,
                              void* d_out, int out_size, void* d_ws, size_t ws_size,
                              hipStream_t stream) {
    const float* x  = (const float*)d_in[0];
    const float* W1 = (const float*)d_in[1];
    const float* b1 = (const float*)d_in[2];
    const float* W2 = (const float*)d_in[3];
    const float* b2 = (const float*)d_in[4];
    const float* W3 = (const float*)d_in[5];
    const float* b3 = (const float*)d_in[6];
    const float* Wh = (const float*)d_in[7];
    const float* bh = (const float*)d_in[8];
    const int* edge_index = (const int*)d_in[9];
    const int* batch = (const int*)d_in[10];
    (void)n_in; (void)ws_size;

    const int N = in_sizes[10];
    const int E = in_sizes[9] / 2;
    const int G = out_size / 8;
    const int* esrc = edge_index;
    const int* edst = edge_index + E;

    size_t off = 0;
    auto take = [&](size_t bytes) {
        void* p = (char*)d_ws + off;
        off += (bytes + 255) & ~(size_t)255;
        return p;
    };
    int*   deg      = (int*)take((size_t)N * 4);
    float* dinv     = (float*)take((size_t)N * 4);
    int*   row_ptr  = (int*)take((size_t)(N + 1) * 4);
    int*   rank     = (int*)take((size_t)E * 4);
    int*   csr_src  = (int*)take((size_t)(E + N) * 4);
    int*   bsum     = (int*)take(256 * 4);
    int*   boff     = (int*)take(256 * 4);
    int*   gstart   = (int*)take((size_t)(G + 1) * 4);
    float* part     = (float*)take((size_t)G * PSPLIT * 128 * 4);
    float* gpool    = (float*)take((size_t)G * 128 * 4);
    unsigned short* x16  = (unsigned short*)take((size_t)N * 64 * 2);
    unsigned short* h16a = (unsigned short*)take((size_t)N * 128 * 2);
    unsigned short* h16b = (unsigned short*)take((size_t)N * 128 * 2);
    unsigned short* Wt1  = (unsigned short*)take((size_t)128 * 64 * 2);
    unsigned short* Wt2  = (unsigned short*)take((size_t)128 * 128 * 2);
    unsigned short* Wt3  = (unsigned short*)take((size_t)128 * 128 * 2);
    float* bufA     = (float*)take((size_t)N * 128 * 4);

    int nblk = (N + 255) / 256;
    int fgrid = (N + 15) / 16;

    hipMemsetAsync(deg, 0, (size_t)N * 4, stream);

    deg_kernel<<<(E + 255) / 256, 256, 0, stream>>>(edst, deg, rank, E);
    scan_blocksum<<<nblk, 256, 0, stream>>>(deg, bsum, dinv, N);
    scan_offsets<<<1, 256, 0, stream>>>(bsum, boff, nblk);
    scan_rowptr<<<nblk, 256, 0, stream>>>(deg, boff, row_ptr, N);
    fill_kernel<<<(E + N + 255) / 256, 256, 0, stream>>>(esrc, edst, rank, row_ptr, csr_src, E, N);
    x2bf_kernel<<<(N * 64 / 8 + 255) / 256, 256, 0, stream>>>(x, (unsigned*)x16, N * 64 / 8);
    wt_all<<<(40960 + 255) / 256, 256, 0, stream>>>(W1, W2, W3, Wt1, Wt2, Wt3);

    // Fused layers (Agg(x)@W == Agg(x@W) used at layer 1)
    agg_gemm<64,  true,  true ><<<fgrid, 256, 0, stream>>>(x16,  Wt1, b1, h16a, row_ptr, csr_src, dinv, N);
    agg_gemm<128, true,  true ><<<fgrid, 256, 0, stream>>>(h16a, Wt2, b2, h16b, row_ptr, csr_src, dinv, N);
    agg_gemm<128, false, false><<<fgrid, 256, 0, stream>>>(h16b, Wt3, b3, bufA, row_ptr, csr_src, dinv, N);

    // Pool (batch sorted -> contiguous ranges): two-stage, then head
    gstart_bs<<<1, 256, 0, stream>>>(batch, gstart, N, G);
    pool_part<<<G * PSPLIT, 256, 0, stream>>>(bufA, gstart, part);
    pool_final<<<G, 128, 0, stream>>>(part, gstart, gpool);
    head_kernel<<<(G * 8 + 255) / 256, 256, 0, stream>>>(gpool, Wh, bh, (float*)d_out, G);
}

// Round 12
// 242.578 us; speedup vs baseline: 1.0814x; 1.0814x over previous
//
#include <hip/hip_runtime.h>

typedef short bf8_t __attribute__((ext_vector_type(8)));   // 8 bf16 in 4 VGPRs
typedef float f32x4 __attribute__((ext_vector_type(4)));

__device__ inline unsigned short f2bf(float f) {        // RNE f32 -> bf16
    unsigned u = __float_as_uint(f);
    return (unsigned short)((u + 0x7fff + ((u >> 16) & 1)) >> 16);
}

// ---------------- CSR construction ----------------

__global__ void deg_kernel(const int* __restrict__ dst, int* __restrict__ deg,
                           int* __restrict__ rank, int E) {
    int e = blockIdx.x * 256 + threadIdx.x;
    if (e < E) rank[e] = atomicAdd(&deg[dst[e]], 1);
}

// block sums of (deg+1) for rowptr scan; also emits dinv = rsqrt(deg+1)
__global__ void scan_blocksum(const int* __restrict__ deg, int* __restrict__ bsum,
                              float* __restrict__ dinv, int n) {
    int i = blockIdx.x * 256 + threadIdx.x;
    int d = (i < n) ? (deg[i] + 1) : 0;
    if (i < n) dinv[i] = rsqrtf((float)d);
    int v = d;
    for (int off = 32; off > 0; off >>= 1) v += __shfl_down(v, off, 64);
    __shared__ int ws[4];
    if ((threadIdx.x & 63) == 0) ws[threadIdx.x >> 6] = v;
    __syncthreads();
    if (threadIdx.x == 0) bsum[blockIdx.x] = ws[0] + ws[1] + ws[2] + ws[3];
}

__global__ void scan_offsets(const int* __restrict__ bsum, int* __restrict__ boff, int nblk) {
    __shared__ int buf[256];
    int tid = threadIdx.x;
    int v = (tid < nblk) ? bsum[tid] : 0;
    buf[tid] = v;
    __syncthreads();
    for (int off = 1; off < 256; off <<= 1) {
        int t = (tid >= off) ? buf[tid - off] : 0;
        __syncthreads();
        buf[tid] += t;
        __syncthreads();
    }
    if (tid < nblk) boff[tid] = buf[tid] - v;   // exclusive
}

__global__ void scan_rowptr(const int* __restrict__ deg, const int* __restrict__ boff,
                            int* __restrict__ row_ptr, int n) {
    __shared__ int buf[256];
    int tid = threadIdx.x;
    int i = blockIdx.x * 256 + tid;
    int v = (i < n) ? (deg[i] + 1) : 0;
    buf[tid] = v;
    __syncthreads();
    for (int off = 1; off < 256; off <<= 1) {
        int t = (tid >= off) ? buf[tid - off] : 0;
        __syncthreads();
        buf[tid] += t;
        __syncthreads();
    }
    int excl = buf[tid] - v + boff[blockIdx.x];
    if (i < n) row_ptr[i] = excl;
    if (i == n - 1) row_ptr[n] = excl + v;
}

// Atomic-free fill: pos = row_ptr[dst] + 1 + rank (self-loop deterministically at slot 0).
__global__ void fill_kernel(const int* __restrict__ src, const int* __restrict__ dst,
                            const int* __restrict__ rank,
                            const int* __restrict__ row_ptr,
                            int* __restrict__ csr_src, int E, int n) {
    int e = blockIdx.x * 256 + threadIdx.x;
    if (e < E) {
        int s = src[e], d = dst[e];
        int pos = row_ptr[d] + 1 + rank[e];
        __builtin_nontemporal_store(s, &csr_src[pos]);
    } else if (e < E + n) {
        int s = e - E;
        __builtin_nontemporal_store(s, &csr_src[row_ptr[s]]);
    }
}

// Convert x to bf16 PRE-SCALED by dinv[node]: x16[s] = dinv[s]*x[s].
// The gather is then a pure sum (no per-edge dinv load).
__global__ void x2bf_kernel(const float* __restrict__ x, const float* __restrict__ dinv,
                            unsigned* __restrict__ x16, int total8) {   // total8 = N*64/8
    int i = blockIdx.x * 256 + threadIdx.x;
    if (i >= total8) return;
    float dn = dinv[i >> 3];                 // 8 elems per thread, 64 per node
    const float4* x4 = (const float4*)x;
    float4 a = x4[i * 2], b = x4[i * 2 + 1];
    uint4 o;
    o.x = (unsigned)f2bf(a.x * dn) | ((unsigned)f2bf(a.y * dn) << 16);
    o.y = (unsigned)f2bf(a.z * dn) | ((unsigned)f2bf(a.w * dn) << 16);
    o.z = (unsigned)f2bf(b.x * dn) | ((unsigned)f2bf(b.y * dn) << 16);
    o.w = (unsigned)f2bf(b.z * dn) | ((unsigned)f2bf(b.w * dn) << 16);
    ((uint4*)x16)[i] = o;
}

// All three W [K x 128] fp32 -> W^T [128 x K] bf16, one launch (40960 elems).
__global__ void wt_all(const float* __restrict__ W1, const float* __restrict__ W2,
                       const float* __restrict__ W3,
                       unsigned short* __restrict__ Wt1, unsigned short* __restrict__ Wt2,
                       unsigned short* __restrict__ Wt3) {
    int i = blockIdx.x * 256 + threadIdx.x;
    if (i < 8192) {                       // W1: K=64
        int nn = i / 64, k = i - nn * 64;
        Wt1[i] = f2bf(W1[k * 128 + nn]);
    } else if (i < 24576) {               // W2: K=128
        int j = i - 8192;
        int nn = j / 128, k = j - nn * 128;
        Wt2[j] = f2bf(W2[k * 128 + nn]);
    } else if (i < 40960) {               // W3: K=128
        int j = i - 24576;
        int nn = j / 128, k = j - nn * 128;
        Wt3[j] = f2bf(W3[k * 128 + nn]);
    }
}

// ---------------- Fused aggregate + MFMA GEMM ----------------
// Input rows are PRE-SCALED (in[s] = dinv[s]*h[s]), so gather = plain sum;
// pack applies dinv[node]; epilogue (BF16OUT) pre-scales the next layer's operand
// by dinv[orow]. Block = 16 nodes, 4 waves; wave w aggregates LDS rows w*4..+3
// (XOR-swizzled), then computes output cols w*32..+31 via 16x16x32 bf16 MFMA.
// 2-deep unroll (R11 showed 4-deep regresses: VGPR/occupancy, not MLP, binds).

__device__ inline void bf8_add(uint4 a, float* acc) {
#pragma unroll
    for (int j = 0; j < 4; ++j) {
        unsigned u = ((const unsigned*)&a)[j];
        acc[2 * j]     += __uint_as_float(u << 16);
        acc[2 * j + 1] += __uint_as_float(u & 0xffff0000u);
    }
}

__device__ inline uint4 pack_bf8(const float* v, float dn) {
    uint4 o;
    o.x = (unsigned)f2bf(v[0] * dn) | ((unsigned)f2bf(v[1] * dn) << 16);
    o.y = (unsigned)f2bf(v[2] * dn) | ((unsigned)f2bf(v[3] * dn) << 16);
    o.z = (unsigned)f2bf(v[4] * dn) | ((unsigned)f2bf(v[5] * dn) << 16);
    o.w = (unsigned)f2bf(v[6] * dn) | ((unsigned)f2bf(v[7] * dn) << 16);
    return o;
}

template<int K, bool RELU, bool BF16OUT>
__global__ __launch_bounds__(256) void agg_gemm(
        const unsigned short* __restrict__ in, const unsigned short* __restrict__ Wt16,
        const float* __restrict__ bias, void* __restrict__ outp,
        const int* __restrict__ row_ptr, const int* __restrict__ csr_src,
        const float* __restrict__ dinv, int n) {
    constexpr int KS = K / 32;
    __shared__ unsigned short As[16 * K];
    int w = threadIdx.x >> 6, lane = threadIdx.x & 63;
    int base = blockIdx.x * 16;
    int lr = lane & 15, lk = lane >> 4;

    // Preload W frags (cols w*32..+31) before gather for latency overlap.
    bf8_t B[2][KS];
#pragma unroll
    for (int f = 0; f < 2; ++f) {
        int col = w * 32 + f * 16 + lr;
#pragma unroll
        for (int ks = 0; ks < KS; ++ks)
            B[f][ks] = *reinterpret_cast<const bf8_t*>(&Wt16[(size_t)col * K + ks * 32 + lk * 8]);
    }

    const uint4* in4 = (const uint4*)in;
    for (int nd = 0; nd < 4; ++nd) {
        int row = w * 4 + nd;
        int node = base + row;
        float acc[8] = {0.f, 0.f, 0.f, 0.f, 0.f, 0.f, 0.f, 0.f};
        if (node < n) {
            int beg = row_ptr[node], end = row_ptr[node + 1];
            if (K == 128) {          // row = 16 uint4; 16 lanes/edge, 4 groups, 2-deep
                int col = lane & 15;
                int i = beg + (lane >> 4);
                for (; i + 4 < end; i += 8) {
                    int s0 = csr_src[i], s1 = csr_src[i + 4];
                    uint4 a = in4[(size_t)s0 * 16 + col];
                    uint4 b = in4[(size_t)s1 * 16 + col];
                    bf8_add(a, acc);
                    bf8_add(b, acc);
                }
                if (i < end) bf8_add(in4[(size_t)csr_src[i] * 16 + col], acc);
#pragma unroll
                for (int j = 0; j < 8; ++j) {
                    acc[j] += __shfl_xor(acc[j], 16, 64);
                    acc[j] += __shfl_xor(acc[j], 32, 64);
                }
            } else {                 // K==64: row = 8 uint4; 8 lanes/edge, 8 groups, 2-deep
                int col = lane & 7;
                int i = beg + (lane >> 3);
                for (; i + 8 < end; i += 16) {
                    int s0 = csr_src[i], s1 = csr_src[i + 8];
                    uint4 a = in4[(size_t)s0 * 8 + col];
                    uint4 b = in4[(size_t)s1 * 8 + col];
                    bf8_add(a, acc);
                    bf8_add(b, acc);
                }
                if (i < end) bf8_add(in4[(size_t)csr_src[i] * 8 + col], acc);
#pragma unroll
                for (int j = 0; j < 8; ++j) {
                    acc[j] += __shfl_xor(acc[j], 8, 64);
                    acc[j] += __shfl_xor(acc[j], 16, 64);
                    acc[j] += __shfl_xor(acc[j], 32, 64);
                }
            }
        }
        // LDS write, swizzled: 16-way bank conflict on read otherwise (row stride % 128B == 0)
        if (lane < K / 8) {
            float dn = (node < n) ? dinv[node] : 0.f;
            uint4 o = pack_bf8(acc, dn);
            int off = row * K + ((lane * 8) ^ ((row & 7) << 3));
            *(uint4*)&As[off] = o;
        }
    }
    __syncthreads();

    f32x4 pacc[2] = {};
#pragma unroll
    for (int ks = 0; ks < KS; ++ks) {
        int off = lr * K + (((ks * 32) + lk * 8) ^ ((lr & 7) << 3));
        bf8_t a = *reinterpret_cast<const bf8_t*>(&As[off]);
#pragma unroll
        for (int f = 0; f < 2; ++f)
            pacc[f] = __builtin_amdgcn_mfma_f32_16x16x32_bf16(B[f][ks], a, pacc[f], 0, 0, 0);
    }

    int orow = base + lr;
    if (orow < n) {
        float dnx = BF16OUT ? dinv[orow] : 1.f;   // pre-scale next layer's gather operand
#pragma unroll
        for (int f = 0; f < 2; ++f) {
            int c0 = w * 32 + f * 16 + lk * 4;
            float4 bv = *(const float4*)&bias[c0];
            float v0 = pacc[f][0] + bv.x, v1 = pacc[f][1] + bv.y;
            float v2 = pacc[f][2] + bv.z, v3 = pacc[f][3] + bv.w;
            if (RELU) {
                v0 = fmaxf(v0, 0.f); v1 = fmaxf(v1, 0.f);
                v2 = fmaxf(v2, 0.f); v3 = fmaxf(v3, 0.f);
            }
            if (BF16OUT) {
                uint2 o;
                o.x = (unsigned)f2bf(v0 * dnx) | ((unsigned)f2bf(v1 * dnx) << 16);
                o.y = (unsigned)f2bf(v2 * dnx) | ((unsigned)f2bf(v3 * dnx) << 16);
                *(uint2*)&((unsigned short*)outp)[(size_t)orow * 128 + c0] = o;
            } else {
                *(float4*)&((float*)outp)[(size_t)orow * 128 + c0] = make_float4(v0, v1, v2, v3);
            }
        }
    }
}

// ---------------- Pooling + head ----------------

__global__ void gstart_bs(const int* __restrict__ batch, int* __restrict__ gstart,
                          int n, int G) {
    int g = blockIdx.x * blockDim.x + threadIdx.x;
    if (g > G) return;
    int lo = 0, hi = n;
    while (lo < hi) {
        int mid = (lo + hi) >> 1;
        if (batch[mid] < g) lo = mid + 1; else hi = mid;
    }
    gstart[g] = lo;
}

#define PSPLIT 16
__global__ __launch_bounds__(256) void pool_part(
        const float* __restrict__ h, const int* __restrict__ gstart,
        float* __restrict__ part) {
    int g = blockIdx.x >> 4, sp = blockIdx.x & (PSPLIT - 1);
    int tid = threadIdx.x;
    int c = tid & 127, rs = tid >> 7;
    int beg = gstart[g], end = gstart[g + 1];
    int len = end - beg;
    int chunk = (len + PSPLIT - 1) >> 4;
    int r0 = beg + sp * chunk;
    int r1 = min(r0 + chunk, end);
    float acc = 0.f;
    for (int r = r0 + rs; r < r1; r += 2)
        acc += h[(size_t)r * 128 + c];
    __shared__ float buf[256];
    buf[tid] = acc;
    __syncthreads();
    if (rs == 0)
        part[(size_t)blockIdx.x * 128 + c] = buf[c] + buf[c + 128];
}

__global__ __launch_bounds__(128) void pool_final(
        const float* __restrict__ part, const int* __restrict__ gstart,
        float* __restrict__ gout) {
    int g = blockIdx.x;
    int c = threadIdx.x;
    float acc = 0.f;
#pragma unroll
    for (int sp = 0; sp < PSPLIT; ++sp)
        acc += part[((size_t)g * PSPLIT + sp) * 128 + c];
    int cnt = gstart[g + 1] - gstart[g];
    gout[g * 128 + c] = acc / fmaxf((float)cnt, 1.f);
}

__global__ void head_kernel(const float* __restrict__ g, const float* __restrict__ Wh,
                            const float* __restrict__ bh, float* __restrict__ out, int G) {
    int tid = blockIdx.x * blockDim.x + threadIdx.x;
    if (tid >= G * 8) return;
    int gi = tid >> 3, o = tid & 7;
    float acc = bh[o];
    for (int k = 0; k < 128; ++k)
        acc = fmaf(g[gi * 128 + k], Wh[k * 8 + o], acc);
    out[tid] = acc;
}

// ---------------- Launch ----------------

extern "C" void kernel_launch(void* const* d_in, const int* in_sizes, int n_in,
                              void* d_out, int out_size, void* d_ws, size_t ws_size,
                              hipStream_t stream) {
    const float* x  = (const float*)d_in[0];
    const float* W1 = (const float*)d_in[1];
    const float* b1 = (const float*)d_in[2];
    const float* W2 = (const float*)d_in[3];
    const float* b2 = (const float*)d_in[4];
    const float* W3 = (const float*)d_in[5];
    const float* b3 = (const float*)d_in[6];
    const float* Wh = (const float*)d_in[7];
    const float* bh = (const float*)d_in[8];
    const int* edge_index = (const int*)d_in[9];
    const int* batch = (const int*)d_in[10];
    (void)n_in; (void)ws_size;

    const int N = in_sizes[10];
    const int E = in_sizes[9] / 2;
    const int G = out_size / 8;
    const int* esrc = edge_index;
    const int* edst = edge_index + E;

    size_t off = 0;
    auto take = [&](size_t bytes) {
        void* p = (char*)d_ws + off;
        off += (bytes + 255) & ~(size_t)255;
        return p;
    };
    int*   deg      = (int*)take((size_t)N * 4);
    float* dinv     = (float*)take((size_t)N * 4);
    int*   row_ptr  = (int*)take((size_t)(N + 1) * 4);
    int*   rank     = (int*)take((size_t)E * 4);
    int*   csr_src  = (int*)take((size_t)(E + N) * 4);
    int*   bsum     = (int*)take(256 * 4);
    int*   boff     = (int*)take(256 * 4);
    int*   gstart   = (int*)take((size_t)(G + 1) * 4);
    float* part     = (float*)take((size_t)G * PSPLIT * 128 * 4);
    float* gpool    = (float*)take((size_t)G * 128 * 4);
    unsigned short* x16  = (unsigned short*)take((size_t)N * 64 * 2);
    unsigned short* h16a = (unsigned short*)take((size_t)N * 128 * 2);
    unsigned short* h16b = (unsigned short*)take((size_t)N * 128 * 2);
    unsigned short* Wt1  = (unsigned short*)take((size_t)128 * 64 * 2);
    unsigned short* Wt2  = (unsigned short*)take((size_t)128 * 128 * 2);
    unsigned short* Wt3  = (unsigned short*)take((size_t)128 * 128 * 2);
    float* bufA     = (float*)take((size_t)N * 128 * 4);

    int nblk = (N + 255) / 256;
    int fgrid = (N + 15) / 16;

    hipMemsetAsync(deg, 0, (size_t)N * 4, stream);

    deg_kernel<<<(E + 255) / 256, 256, 0, stream>>>(edst, deg, rank, E);
    scan_blocksum<<<nblk, 256, 0, stream>>>(deg, bsum, dinv, N);
    scan_offsets<<<1, 256, 0, stream>>>(bsum, boff, nblk);
    scan_rowptr<<<nblk, 256, 0, stream>>>(deg, boff, row_ptr, N);
    fill_kernel<<<(E + N + 255) / 256, 256, 0, stream>>>(esrc, edst, rank, row_ptr, csr_src, E, N);
    x2bf_kernel<<<(N * 64 / 8 + 255) / 256, 256, 0, stream>>>(x, dinv, (unsigned*)x16, N * 64 / 8);
    wt_all<<<(40960 + 255) / 256, 256, 0, stream>>>(W1, W2, W3, Wt1, Wt2, Wt3);

    // Fused layers (Agg(x)@W == Agg(x@W) used at layer 1)
    agg_gemm<64,  true,  true ><<<fgrid, 256, 0, stream>>>(x16,  Wt1, b1, h16a, row_ptr, csr_src, dinv, N);
    agg_gemm<128, true,  true ><<<fgrid, 256, 0, stream>>>(h16a, Wt2, b2, h16b, row_ptr, csr_src, dinv, N);
    agg_gemm<128, false, false><<<fgrid, 256, 0, stream>>>(h16b, Wt3, b3, bufA, row_ptr, csr_src, dinv, N);

    // Pool (batch sorted -> contiguous ranges): two-stage, then head
    gstart_bs<<<1, 256, 0, stream>>>(batch, gstart, N, G);
    pool_part<<<G * PSPLIT, 256, 0, stream>>>(bufA, gstart, part);
    pool_final<<<G, 128, 0, stream>>>(part, gstart, gpool);
    head_kernel<<<(G * 8 + 255) / 256, 256, 0, stream>>>(gpool, Wh, bh, (float*)d_out, G);
}

// Round 13
// 226.865 us; speedup vs baseline: 1.1563x; 1.0693x over previous
//
#include <hip/hip_runtime.h>

typedef short bf8_t __attribute__((ext_vector_type(8)));   // 8 bf16 in 4 VGPRs
typedef float f32x4 __attribute__((ext_vector_type(4)));

__device__ inline unsigned short f2bf(float f) {        // RNE f32 -> bf16
    unsigned u = __float_as_uint(f);
    return (unsigned short)((u + 0x7fff + ((u >> 16) & 1)) >> 16);
}

// ---------------- CSR construction ----------------

__global__ void deg_kernel(const int* __restrict__ dst, int* __restrict__ deg,
                           int* __restrict__ rank, int E) {
    int e = blockIdx.x * 256 + threadIdx.x;
    if (e < E) rank[e] = atomicAdd(&deg[dst[e]], 1);
}

// block sums of (deg+1) for rowptr scan; also emits dinv = rsqrt(deg+1)
__global__ void scan_blocksum(const int* __restrict__ deg, int* __restrict__ bsum,
                              float* __restrict__ dinv, int n) {
    int i = blockIdx.x * 256 + threadIdx.x;
    int d = (i < n) ? (deg[i] + 1) : 0;
    if (i < n) dinv[i] = rsqrtf((float)d);
    int v = d;
    for (int off = 32; off > 0; off >>= 1) v += __shfl_down(v, off, 64);
    __shared__ int ws[4];
    if ((threadIdx.x & 63) == 0) ws[threadIdx.x >> 6] = v;
    __syncthreads();
    if (threadIdx.x == 0) bsum[blockIdx.x] = ws[0] + ws[1] + ws[2] + ws[3];
}

__global__ void scan_offsets(const int* __restrict__ bsum, int* __restrict__ boff, int nblk) {
    __shared__ int buf[256];
    int tid = threadIdx.x;
    int v = (tid < nblk) ? bsum[tid] : 0;
    buf[tid] = v;
    __syncthreads();
    for (int off = 1; off < 256; off <<= 1) {
        int t = (tid >= off) ? buf[tid - off] : 0;
        __syncthreads();
        buf[tid] += t;
        __syncthreads();
    }
    if (tid < nblk) boff[tid] = buf[tid] - v;   // exclusive
}

__global__ void scan_rowptr(const int* __restrict__ deg, const int* __restrict__ boff,
                            int* __restrict__ row_ptr, int n) {
    __shared__ int buf[256];
    int tid = threadIdx.x;
    int i = blockIdx.x * 256 + tid;
    int v = (i < n) ? (deg[i] + 1) : 0;
    buf[tid] = v;
    __syncthreads();
    for (int off = 1; off < 256; off <<= 1) {
        int t = (tid >= off) ? buf[tid - off] : 0;
        __syncthreads();
        buf[tid] += t;
        __syncthreads();
    }
    int excl = buf[tid] - v + boff[blockIdx.x];
    if (i < n) row_ptr[i] = excl;
    if (i == n - 1) row_ptr[n] = excl + v;
}

// Atomic-free fill: pos = row_ptr[dst] + 1 + rank (self-loop deterministically at slot 0).
__global__ void fill_kernel(const int* __restrict__ src, const int* __restrict__ dst,
                            const int* __restrict__ rank,
                            const int* __restrict__ row_ptr,
                            int* __restrict__ csr_src, int E, int n) {
    int e = blockIdx.x * 256 + threadIdx.x;
    if (e < E) {
        int s = src[e], d = dst[e];
        int pos = row_ptr[d] + 1 + rank[e];
        __builtin_nontemporal_store(s, &csr_src[pos]);
    } else if (e < E + n) {
        int s = e - E;
        __builtin_nontemporal_store(s, &csr_src[row_ptr[s]]);
    }
}

// Convert x to bf16 PRE-SCALED by dinv[node]: x16[s] = dinv[s]*x[s].
__global__ void x2bf_kernel(const float* __restrict__ x, const float* __restrict__ dinv,
                            unsigned* __restrict__ x16, int total8) {   // total8 = N*64/8
    int i = blockIdx.x * 256 + threadIdx.x;
    if (i >= total8) return;
    float dn = dinv[i >> 3];                 // 8 elems per thread, 64 per node
    const float4* x4 = (const float4*)x;
    float4 a = x4[i * 2], b = x4[i * 2 + 1];
    uint4 o;
    o.x = (unsigned)f2bf(a.x * dn) | ((unsigned)f2bf(a.y * dn) << 16);
    o.y = (unsigned)f2bf(a.z * dn) | ((unsigned)f2bf(a.w * dn) << 16);
    o.z = (unsigned)f2bf(b.x * dn) | ((unsigned)f2bf(b.y * dn) << 16);
    o.w = (unsigned)f2bf(b.z * dn) | ((unsigned)f2bf(b.w * dn) << 16);
    ((uint4*)x16)[i] = o;
}

// All three W [K x 128] fp32 -> W^T [128 x K] bf16, one launch (40960 elems).
__global__ void wt_all(const float* __restrict__ W1, const float* __restrict__ W2,
                       const float* __restrict__ W3,
                       unsigned short* __restrict__ Wt1, unsigned short* __restrict__ Wt2,
                       unsigned short* __restrict__ Wt3) {
    int i = blockIdx.x * 256 + threadIdx.x;
    if (i < 8192) {                       // W1: K=64
        int nn = i / 64, k = i - nn * 64;
        Wt1[i] = f2bf(W1[k * 128 + nn]);
    } else if (i < 24576) {               // W2: K=128
        int j = i - 8192;
        int nn = j / 128, k = j - nn * 128;
        Wt2[j] = f2bf(W2[k * 128 + nn]);
    } else if (i < 40960) {               // W3: K=128
        int j = i - 24576;
        int nn = j / 128, k = j - nn * 128;
        Wt3[j] = f2bf(W3[k * 128 + nn]);
    }
}

// ---------------- Fused aggregate + MFMA GEMM ----------------
// Input rows PRE-SCALED (in[s] = dinv[s]*h[s]) -> gather = plain sum.
// Block = 16 nodes, 4 waves. GATHER: each wave's four 16-lane groups walk four
// nodes CONCURRENTLY (time = max degree, not sum; no cross-group reduce for
// K=128 since 16 lanes x 16 B = full 256 B row). 2-deep unroll -> 8 rows in
// flight/wave at no extra VGPR (R11: 4-deep VGPR cost regresses).
// GEMM: wave w computes output cols w*32..+31 via 16x16x32 bf16 MFMA from the
// XOR-swizzled LDS A-tile.

__device__ inline void bf8_add(uint4 a, float* acc) {
#pragma unroll
    for (int j = 0; j < 4; ++j) {
        unsigned u = ((const unsigned*)&a)[j];
        acc[2 * j]     += __uint_as_float(u << 16);
        acc[2 * j + 1] += __uint_as_float(u & 0xffff0000u);
    }
}

__device__ inline uint4 pack_bf8(const float* v, float dn) {
    uint4 o;
    o.x = (unsigned)f2bf(v[0] * dn) | ((unsigned)f2bf(v[1] * dn) << 16);
    o.y = (unsigned)f2bf(v[2] * dn) | ((unsigned)f2bf(v[3] * dn) << 16);
    o.z = (unsigned)f2bf(v[4] * dn) | ((unsigned)f2bf(v[5] * dn) << 16);
    o.w = (unsigned)f2bf(v[6] * dn) | ((unsigned)f2bf(v[7] * dn) << 16);
    return o;
}

template<int K, bool RELU, bool BF16OUT>
__global__ __launch_bounds__(256) void agg_gemm(
        const unsigned short* __restrict__ in, const unsigned short* __restrict__ Wt16,
        const float* __restrict__ bias, void* __restrict__ outp,
        const int* __restrict__ row_ptr, const int* __restrict__ csr_src,
        const float* __restrict__ dinv, int n) {
    constexpr int KS = K / 32;
    __shared__ unsigned short As[16 * K];
    int w = threadIdx.x >> 6, lane = threadIdx.x & 63;
    int base = blockIdx.x * 16;
    int lr = lane & 15, lk = lane >> 4;

    // Preload W frags (cols w*32..+31) before gather for latency overlap.
    bf8_t B[2][KS];
#pragma unroll
    for (int f = 0; f < 2; ++f) {
        int col = w * 32 + f * 16 + lr;
#pragma unroll
        for (int ks = 0; ks < KS; ++ks)
            B[f][ks] = *reinterpret_cast<const bf8_t*>(&Wt16[(size_t)col * K + ks * 32 + lk * 8]);
    }

    const uint4* in4 = (const uint4*)in;
    int g = lane >> 4;                     // group = which of the wave's 4 nodes
    int row = w * 4 + g;
    int node = base + row;
    float acc[8] = {0.f, 0.f, 0.f, 0.f, 0.f, 0.f, 0.f, 0.f};

    if (K == 128) {
        // 16 lanes own the whole 256 B row; groups diverge only in loop length.
        int col = lane & 15;
        if (node < n) {
            int beg = row_ptr[node], end = row_ptr[node + 1];
            int i = beg;
            for (; i + 1 < end; i += 2) {
                int s0 = csr_src[i], s1 = csr_src[i + 1];
                uint4 a = in4[(size_t)s0 * 16 + col];
                uint4 b = in4[(size_t)s1 * 16 + col];
                bf8_add(a, acc);
                bf8_add(b, acc);
            }
            if (i < end) bf8_add(in4[(size_t)csr_src[i] * 16 + col], acc);
        }
        float dn = (node < n) ? dinv[node] : 0.f;
        int off = row * K + ((col * 8) ^ ((row & 7) << 3));
        *(uint4*)&As[off] = pack_bf8(acc, dn);   // all 64 lanes write
    } else {
        // K==64: row = 128 B = 8 uint4. Group's two 8-lane halves take alternating
        // edges (2 edges/step), 2-deep -> 4 in flight/node; one shfl_xor(8) combine.
        int sub = (lane >> 3) & 1;
        int col = lane & 7;
        if (node < n) {
            int beg = row_ptr[node], end = row_ptr[node + 1];
            int i = beg + sub;
            for (; i + 2 < end; i += 4) {
                int s0 = csr_src[i], s1 = csr_src[i + 2];
                uint4 a = in4[(size_t)s0 * 8 + col];
                uint4 b = in4[(size_t)s1 * 8 + col];
                bf8_add(a, acc);
                bf8_add(b, acc);
            }
            if (i < end) bf8_add(in4[(size_t)csr_src[i] * 8 + col], acc);
        }
#pragma unroll
        for (int j = 0; j < 8; ++j)
            acc[j] += __shfl_xor(acc[j], 8, 64);
        if (sub == 0) {
            float dn = (node < n) ? dinv[node] : 0.f;
            int off = row * K + ((col * 8) ^ ((row & 7) << 3));
            *(uint4*)&As[off] = pack_bf8(acc, dn);
        }
    }
    __syncthreads();

    f32x4 pacc[2] = {};
#pragma unroll
    for (int ks = 0; ks < KS; ++ks) {
        int off = lr * K + (((ks * 32) + lk * 8) ^ ((lr & 7) << 3));
        bf8_t a = *reinterpret_cast<const bf8_t*>(&As[off]);
#pragma unroll
        for (int f = 0; f < 2; ++f)
            pacc[f] = __builtin_amdgcn_mfma_f32_16x16x32_bf16(B[f][ks], a, pacc[f], 0, 0, 0);
    }

    int orow = base + lr;
    if (orow < n) {
        float dnx = BF16OUT ? dinv[orow] : 1.f;   // pre-scale next layer's gather operand
#pragma unroll
        for (int f = 0; f < 2; ++f) {
            int c0 = w * 32 + f * 16 + lk * 4;
            float4 bv = *(const float4*)&bias[c0];
            float v0 = pacc[f][0] + bv.x, v1 = pacc[f][1] + bv.y;
            float v2 = pacc[f][2] + bv.z, v3 = pacc[f][3] + bv.w;
            if (RELU) {
                v0 = fmaxf(v0, 0.f); v1 = fmaxf(v1, 0.f);
                v2 = fmaxf(v2, 0.f); v3 = fmaxf(v3, 0.f);
            }
            if (BF16OUT) {
                uint2 o;
                o.x = (unsigned)f2bf(v0 * dnx) | ((unsigned)f2bf(v1 * dnx) << 16);
                o.y = (unsigned)f2bf(v2 * dnx) | ((unsigned)f2bf(v3 * dnx) << 16);
                *(uint2*)&((unsigned short*)outp)[(size_t)orow * 128 + c0] = o;
            } else {
                *(float4*)&((float*)outp)[(size_t)orow * 128 + c0] = make_float4(v0, v1, v2, v3);
            }
        }
    }
}

// ---------------- Pooling + head ----------------

__global__ void gstart_bs(const int* __restrict__ batch, int* __restrict__ gstart,
                          int n, int G) {
    int g = blockIdx.x * blockDim.x + threadIdx.x;
    if (g > G) return;
    int lo = 0, hi = n;
    while (lo < hi) {
        int mid = (lo + hi) >> 1;
        if (batch[mid] < g) lo = mid + 1; else hi = mid;
    }
    gstart[g] = lo;
}

#define PSPLIT 16
__global__ __launch_bounds__(256) void pool_part(
        const float* __restrict__ h, const int* __restrict__ gstart,
        float* __restrict__ part) {
    int g = blockIdx.x >> 4, sp = blockIdx.x & (PSPLIT - 1);
    int tid = threadIdx.x;
    int c = tid & 127, rs = tid >> 7;
    int beg = gstart[g], end = gstart[g + 1];
    int len = end - beg;
    int chunk = (len + PSPLIT - 1) >> 4;
    int r0 = beg + sp * chunk;
    int r1 = min(r0 + chunk, end);
    float acc = 0.f;
    for (int r = r0 + rs; r < r1; r += 2)
        acc += h[(size_t)r * 128 + c];
    __shared__ float buf[256];
    buf[tid] = acc;
    __syncthreads();
    if (rs == 0)
        part[(size_t)blockIdx.x * 128 + c] = buf[c] + buf[c + 128];
}

__global__ __launch_bounds__(128) void pool_final(
        const float* __restrict__ part, const int* __restrict__ gstart,
        float* __restrict__ gout) {
    int g = blockIdx.x;
    int c = threadIdx.x;
    float acc = 0.f;
#pragma unroll
    for (int sp = 0; sp < PSPLIT; ++sp)
        acc += part[((size_t)g * PSPLIT + sp) * 128 + c];
    int cnt = gstart[g + 1] - gstart[g];
    gout[g * 128 + c] = acc / fmaxf((float)cnt, 1.f);
}

__global__ void head_kernel(const float* __restrict__ g, const float* __restrict__ Wh,
                            const float* __restrict__ bh, float* __restrict__ out, int G) {
    int tid = blockIdx.x * blockDim.x + threadIdx.x;
    if (tid >= G * 8) return;
    int gi = tid >> 3, o = tid & 7;
    float acc = bh[o];
    for (int k = 0; k < 128; ++k)
        acc = fmaf(g[gi * 128 + k], Wh[k * 8 + o], acc);
    out[tid] = acc;
}

// ---------------- Launch ----------------

extern "C" void kernel_launch(void* const* d_in, const int* in_sizes, int n_in,
                              void* d_out, int out_size, void* d_ws, size_t ws_size,
                              hipStream_t stream) {
    const float* x  = (const float*)d_in[0];
    const float* W1 = (const float*)d_in[1];
    const float* b1 = (const float*)d_in[2];
    const float* W2 = (const float*)d_in[3];
    const float* b2 = (const float*)d_in[4];
    const float* W3 = (const float*)d_in[5];
    const float* b3 = (const float*)d_in[6];
    const float* Wh = (const float*)d_in[7];
    const float* bh = (const float*)d_in[8];
    const int* edge_index = (const int*)d_in[9];
    const int* batch = (const int*)d_in[10];
    (void)n_in; (void)ws_size;

    const int N = in_sizes[10];
    const int E = in_sizes[9] / 2;
    const int G = out_size / 8;
    const int* esrc = edge_index;
    const int* edst = edge_index + E;

    size_t off = 0;
    auto take = [&](size_t bytes) {
        void* p = (char*)d_ws + off;
        off += (bytes + 255) & ~(size_t)255;
        return p;
    };
    int*   deg      = (int*)take((size_t)N * 4);
    float* dinv     = (float*)take((size_t)N * 4);
    int*   row_ptr  = (int*)take((size_t)(N + 1) * 4);
    int*   rank     = (int*)take((size_t)E * 4);
    int*   csr_src  = (int*)take((size_t)(E + N) * 4);
    int*   bsum     = (int*)take(256 * 4);
    int*   boff     = (int*)take(256 * 4);
    int*   gstart   = (int*)take((size_t)(G + 1) * 4);
    float* part     = (float*)take((size_t)G * PSPLIT * 128 * 4);
    float* gpool    = (float*)take((size_t)G * 128 * 4);
    unsigned short* x16  = (unsigned short*)take((size_t)N * 64 * 2);
    unsigned short* h16a = (unsigned short*)take((size_t)N * 128 * 2);
    unsigned short* h16b = (unsigned short*)take((size_t)N * 128 * 2);
    unsigned short* Wt1  = (unsigned short*)take((size_t)128 * 64 * 2);
    unsigned short* Wt2  = (unsigned short*)take((size_t)128 * 128 * 2);
    unsigned short* Wt3  = (unsigned short*)take((size_t)128 * 128 * 2);
    float* bufA     = (float*)take((size_t)N * 128 * 4);

    int nblk = (N + 255) / 256;
    int fgrid = (N + 15) / 16;

    hipMemsetAsync(deg, 0, (size_t)N * 4, stream);

    deg_kernel<<<(E + 255) / 256, 256, 0, stream>>>(edst, deg, rank, E);
    scan_blocksum<<<nblk, 256, 0, stream>>>(deg, bsum, dinv, N);
    scan_offsets<<<1, 256, 0, stream>>>(bsum, boff, nblk);
    scan_rowptr<<<nblk, 256, 0, stream>>>(deg, boff, row_ptr, N);
    fill_kernel<<<(E + N + 255) / 256, 256, 0, stream>>>(esrc, edst, rank, row_ptr, csr_src, E, N);
    x2bf_kernel<<<(N * 64 / 8 + 255) / 256, 256, 0, stream>>>(x, dinv, (unsigned*)x16, N * 64 / 8);
    wt_all<<<(40960 + 255) / 256, 256, 0, stream>>>(W1, W2, W3, Wt1, Wt2, Wt3);

    // Fused layers (Agg(x)@W == Agg(x@W) used at layer 1)
    agg_gemm<64,  true,  true ><<<fgrid, 256, 0, stream>>>(x16,  Wt1, b1, h16a, row_ptr, csr_src, dinv, N);
    agg_gemm<128, true,  true ><<<fgrid, 256, 0, stream>>>(h16a, Wt2, b2, h16b, row_ptr, csr_src, dinv, N);
    agg_gemm<128, false, false><<<fgrid, 256, 0, stream>>>(h16b, Wt3, b3, bufA, row_ptr, csr_src, dinv, N);

    // Pool (batch sorted -> contiguous ranges): two-stage, then head
    gstart_bs<<<1, 256, 0, stream>>>(batch, gstart, N, G);
    pool_part<<<G * PSPLIT, 256, 0, stream>>>(bufA, gstart, part);
    pool_final<<<G, 128, 0, stream>>>(part, gstart, gpool);
    head_kernel<<<(G * 8 + 255) / 256, 256, 0, stream>>>(gpool, Wh, bh, (float*)d_out, G);
}

// Round 14
// 224.492 us; speedup vs baseline: 1.1685x; 1.0106x over previous
//
#include <hip/hip_runtime.h>

typedef short bf8_t __attribute__((ext_vector_type(8)));   // 8 bf16 in 4 VGPRs
typedef float f32x4 __attribute__((ext_vector_type(4)));
typedef unsigned short u16;

__device__ inline u16 f2bf(float f) {        // RNE f32 -> bf16
    unsigned u = __float_as_uint(f);
    return (u16)((u + 0x7fff + ((u >> 16) & 1)) >> 16);
}

// ---------------- CSR construction ----------------

__global__ void deg_kernel(const int* __restrict__ dst, int* __restrict__ deg,
                           u16* __restrict__ rank, int E) {
    int e = blockIdx.x * 256 + threadIdx.x;
    if (e < E) rank[e] = (u16)atomicAdd(&deg[dst[e]], 1);
}

// block sums of (deg+1) for rowptr scan; also emits dinv = rsqrt(deg+1)
__global__ void scan_blocksum(const int* __restrict__ deg, int* __restrict__ bsum,
                              float* __restrict__ dinv, int n) {
    int i = blockIdx.x * 256 + threadIdx.x;
    int d = (i < n) ? (deg[i] + 1) : 0;
    if (i < n) dinv[i] = rsqrtf((float)d);
    int v = d;
    for (int off = 32; off > 0; off >>= 1) v += __shfl_down(v, off, 64);
    __shared__ int ws[4];
    if ((threadIdx.x & 63) == 0) ws[threadIdx.x >> 6] = v;
    __syncthreads();
    if (threadIdx.x == 0) bsum[blockIdx.x] = ws[0] + ws[1] + ws[2] + ws[3];
}

__global__ void scan_offsets(const int* __restrict__ bsum, int* __restrict__ boff, int nblk) {
    __shared__ int buf[256];
    int tid = threadIdx.x;
    int v = (tid < nblk) ? bsum[tid] : 0;
    buf[tid] = v;
    __syncthreads();
    for (int off = 1; off < 256; off <<= 1) {
        int t = (tid >= off) ? buf[tid - off] : 0;
        __syncthreads();
        buf[tid] += t;
        __syncthreads();
    }
    if (tid < nblk) boff[tid] = buf[tid] - v;   // exclusive
}

__global__ void scan_rowptr(const int* __restrict__ deg, const int* __restrict__ boff,
                            int* __restrict__ row_ptr, int n) {
    __shared__ int buf[256];
    int tid = threadIdx.x;
    int i = blockIdx.x * 256 + tid;
    int v = (i < n) ? (deg[i] + 1) : 0;
    buf[tid] = v;
    __syncthreads();
    for (int off = 1; off < 256; off <<= 1) {
        int t = (tid >= off) ? buf[tid - off] : 0;
        __syncthreads();
        buf[tid] += t;
        __syncthreads();
    }
    int excl = buf[tid] - v + boff[blockIdx.x];
    if (i < n) row_ptr[i] = excl;
    if (i == n - 1) row_ptr[n] = excl + v;
}

// Atomic-free fill: pos = row_ptr[dst] + 1 + rank (self-loop at slot 0). ushort ids.
__global__ void fill_kernel(const int* __restrict__ src, const int* __restrict__ dst,
                            const u16* __restrict__ rank,
                            const int* __restrict__ row_ptr,
                            u16* __restrict__ csr_src, int E, int n) {
    int e = blockIdx.x * 256 + threadIdx.x;
    if (e < E) {
        int s = src[e], d = dst[e];
        int pos = row_ptr[d] + 1 + (int)rank[e];
        __builtin_nontemporal_store((u16)s, &csr_src[pos]);
    } else if (e < E + n) {
        int s = e - E;
        __builtin_nontemporal_store((u16)s, &csr_src[row_ptr[s]]);
    }
}

// Convert x to bf16 PRE-SCALED by dinv[node]: x16[s] = dinv[s]*x[s].
__global__ void x2bf_kernel(const float* __restrict__ x, const float* __restrict__ dinv,
                            unsigned* __restrict__ x16, int total8) {   // total8 = N*64/8
    int i = blockIdx.x * 256 + threadIdx.x;
    if (i >= total8) return;
    float dn = dinv[i >> 3];                 // 8 elems per thread, 64 per node
    const float4* x4 = (const float4*)x;
    float4 a = x4[i * 2], b = x4[i * 2 + 1];
    uint4 o;
    o.x = (unsigned)f2bf(a.x * dn) | ((unsigned)f2bf(a.y * dn) << 16);
    o.y = (unsigned)f2bf(a.z * dn) | ((unsigned)f2bf(a.w * dn) << 16);
    o.z = (unsigned)f2bf(b.x * dn) | ((unsigned)f2bf(b.y * dn) << 16);
    o.w = (unsigned)f2bf(b.z * dn) | ((unsigned)f2bf(b.w * dn) << 16);
    ((uint4*)x16)[i] = o;
}

// All three W [K x 128] fp32 -> W^T [128 x K] bf16, one launch (40960 elems).
__global__ void wt_all(const float* __restrict__ W1, const float* __restrict__ W2,
                       const float* __restrict__ W3,
                       u16* __restrict__ Wt1, u16* __restrict__ Wt2,
                       u16* __restrict__ Wt3) {
    int i = blockIdx.x * 256 + threadIdx.x;
    if (i < 8192) {                       // W1: K=64
        int nn = i / 64, k = i - nn * 64;
        Wt1[i] = f2bf(W1[k * 128 + nn]);
    } else if (i < 24576) {               // W2: K=128
        int j = i - 8192;
        int nn = j / 128, k = j - nn * 128;
        Wt2[j] = f2bf(W2[k * 128 + nn]);
    } else if (i < 40960) {               // W3: K=128
        int j = i - 24576;
        int nn = j / 128, k = j - nn * 128;
        Wt3[j] = f2bf(W3[k * 128 + nn]);
    }
}

// ---------------- Fused aggregate + MFMA GEMM ----------------
// Input rows PRE-SCALED (in[s] = dinv[s]*h[s]) -> gather = plain sum.
// Block = 16 nodes, 4 waves; each wave's four 16-lane groups walk 4 nodes
// concurrently. Index stream software-pipelined: next iter's csr entries are
// prefetched into registers while current rows are in flight (csr buffer is
// padded so tail overreads are safe; prefetched values only consumed when real).

__device__ inline void bf8_add(uint4 a, float* acc) {
#pragma unroll
    for (int j = 0; j < 4; ++j) {
        unsigned u = ((const unsigned*)&a)[j];
        acc[2 * j]     += __uint_as_float(u << 16);
        acc[2 * j + 1] += __uint_as_float(u & 0xffff0000u);
    }
}

__device__ inline uint4 pack_bf8(const float* v, float dn) {
    uint4 o;
    o.x = (unsigned)f2bf(v[0] * dn) | ((unsigned)f2bf(v[1] * dn) << 16);
    o.y = (unsigned)f2bf(v[2] * dn) | ((unsigned)f2bf(v[3] * dn) << 16);
    o.z = (unsigned)f2bf(v[4] * dn) | ((unsigned)f2bf(v[5] * dn) << 16);
    o.w = (unsigned)f2bf(v[6] * dn) | ((unsigned)f2bf(v[7] * dn) << 16);
    return o;
}

template<int K, bool RELU, bool BF16OUT>
__global__ __launch_bounds__(256) void agg_gemm(
        const u16* __restrict__ in, const u16* __restrict__ Wt16,
        const float* __restrict__ bias, void* __restrict__ outp,
        const int* __restrict__ row_ptr, const u16* __restrict__ csr_src,
        const float* __restrict__ dinv, int n) {
    constexpr int KS = K / 32;
    __shared__ u16 As[16 * K];
    int w = threadIdx.x >> 6, lane = threadIdx.x & 63;
    int base = blockIdx.x * 16;
    int lr = lane & 15, lk = lane >> 4;

    // Preload W frags (cols w*32..+31) before gather for latency overlap.
    bf8_t B[2][KS];
#pragma unroll
    for (int f = 0; f < 2; ++f) {
        int col = w * 32 + f * 16 + lr;
#pragma unroll
        for (int ks = 0; ks < KS; ++ks)
            B[f][ks] = *reinterpret_cast<const bf8_t*>(&Wt16[(size_t)col * K + ks * 32 + lk * 8]);
    }

    const uint4* in4 = (const uint4*)in;
    int g = lane >> 4;                     // group = which of the wave's 4 nodes
    int row = w * 4 + g;
    int node = base + row;
    float acc[8] = {0.f, 0.f, 0.f, 0.f, 0.f, 0.f, 0.f, 0.f};

    if (K == 128) {
        // 16 lanes own the whole 256 B row; groups diverge only in loop length.
        int col = lane & 15;
        if (node < n) {
            int beg = row_ptr[node], end = row_ptr[node + 1];
            int i = beg;
            int s0 = csr_src[i], s1 = csr_src[i + 1];        // padded overread safe
            for (; i + 1 < end; i += 2) {
                int t0 = csr_src[i + 2], t1 = csr_src[i + 3];
                uint4 a = in4[(size_t)s0 * 16 + col];
                uint4 b = in4[(size_t)s1 * 16 + col];
                bf8_add(a, acc);
                bf8_add(b, acc);
                s0 = t0; s1 = t1;
            }
            if (i < end) bf8_add(in4[(size_t)s0 * 16 + col], acc);
        }
        float dn = (node < n) ? dinv[node] : 0.f;
        int off = row * K + ((col * 8) ^ ((row & 7) << 3));
        *(uint4*)&As[off] = pack_bf8(acc, dn);   // all 64 lanes write
    } else {
        // K==64: row = 128 B = 8 uint4. Group's two 8-lane halves take alternating
        // edges; one shfl_xor(8) combine.
        int sub = (lane >> 3) & 1;
        int col = lane & 7;
        if (node < n) {
            int beg = row_ptr[node], end = row_ptr[node + 1];
            int i = beg + sub;
            int s0 = csr_src[i], s1 = csr_src[i + 2];        // padded overread safe
            for (; i + 2 < end; i += 4) {
                int t0 = csr_src[i + 4], t1 = csr_src[i + 6];
                uint4 a = in4[(size_t)s0 * 8 + col];
                uint4 b = in4[(size_t)s1 * 8 + col];
                bf8_add(a, acc);
                bf8_add(b, acc);
                s0 = t0; s1 = t1;
            }
            if (i < end) bf8_add(in4[(size_t)s0 * 8 + col], acc);
        }
#pragma unroll
        for (int j = 0; j < 8; ++j)
            acc[j] += __shfl_xor(acc[j], 8, 64);
        if (sub == 0) {
            float dn = (node < n) ? dinv[node] : 0.f;
            int off = row * K + ((col * 8) ^ ((row & 7) << 3));
            *(uint4*)&As[off] = pack_bf8(acc, dn);
        }
    }
    __syncthreads();

    f32x4 pacc[2] = {};
#pragma unroll
    for (int ks = 0; ks < KS; ++ks) {
        int off = lr * K + (((ks * 32) + lk * 8) ^ ((lr & 7) << 3));
        bf8_t a = *reinterpret_cast<const bf8_t*>(&As[off]);
#pragma unroll
        for (int f = 0; f < 2; ++f)
            pacc[f] = __builtin_amdgcn_mfma_f32_16x16x32_bf16(B[f][ks], a, pacc[f], 0, 0, 0);
    }

    int orow = base + lr;
    if (orow < n) {
        float dnx = BF16OUT ? dinv[orow] : 1.f;   // pre-scale next layer's gather operand
#pragma unroll
        for (int f = 0; f < 2; ++f) {
            int c0 = w * 32 + f * 16 + lk * 4;
            float4 bv = *(const float4*)&bias[c0];
            float v0 = pacc[f][0] + bv.x, v1 = pacc[f][1] + bv.y;
            float v2 = pacc[f][2] + bv.z, v3 = pacc[f][3] + bv.w;
            if (RELU) {
                v0 = fmaxf(v0, 0.f); v1 = fmaxf(v1, 0.f);
                v2 = fmaxf(v2, 0.f); v3 = fmaxf(v3, 0.f);
            }
            if (BF16OUT) {
                uint2 o;
                o.x = (unsigned)f2bf(v0 * dnx) | ((unsigned)f2bf(v1 * dnx) << 16);
                o.y = (unsigned)f2bf(v2 * dnx) | ((unsigned)f2bf(v3 * dnx) << 16);
                *(uint2*)&((u16*)outp)[(size_t)orow * 128 + c0] = o;
            } else {
                *(float4*)&((float*)outp)[(size_t)orow * 128 + c0] = make_float4(v0, v1, v2, v3);
            }
        }
    }
}

// ---------------- Pooling + head ----------------
// batch sorted -> per-graph contiguous row range via binary search (no gstart array).

__device__ inline int lbound(const int* __restrict__ batch, int n, int g) {
    int lo = 0, hi = n;
    while (lo < hi) {
        int mid = (lo + hi) >> 1;
        if (batch[mid] < g) lo = mid + 1; else hi = mid;
    }
    return lo;
}

#define PSPLIT 16
__global__ __launch_bounds__(256) void pool_part(
        const float* __restrict__ h, const int* __restrict__ batch,
        float* __restrict__ part, int n) {
    int g = blockIdx.x >> 4, sp = blockIdx.x & (PSPLIT - 1);
    int tid = threadIdx.x;
    int c = tid & 127, rs = tid >> 7;
    int beg = lbound(batch, n, g), end = lbound(batch, n, g + 1);
    int len = end - beg;
    int chunk = (len + PSPLIT - 1) >> 4;
    int r0 = beg + sp * chunk;
    int r1 = min(r0 + chunk, end);
    float acc = 0.f;
    for (int r = r0 + rs; r < r1; r += 2)
        acc += h[(size_t)r * 128 + c];
    __shared__ float buf[256];
    buf[tid] = acc;
    __syncthreads();
    if (rs == 0)
        part[(size_t)blockIdx.x * 128 + c] = buf[c] + buf[c + 128];
}

__global__ __launch_bounds__(128) void pool_final(
        const float* __restrict__ part, const int* __restrict__ batch,
        float* __restrict__ gout, int n) {
    int g = blockIdx.x;
    int c = threadIdx.x;
    float acc = 0.f;
#pragma unroll
    for (int sp = 0; sp < PSPLIT; ++sp)
        acc += part[((size_t)g * PSPLIT + sp) * 128 + c];
    int cnt = lbound(batch, n, g + 1) - lbound(batch, n, g);
    gout[g * 128 + c] = acc / fmaxf((float)cnt, 1.f);
}

__global__ void head_kernel(const float* __restrict__ g, const float* __restrict__ Wh,
                            const float* __restrict__ bh, float* __restrict__ out, int G) {
    int tid = blockIdx.x * blockDim.x + threadIdx.x;
    if (tid >= G * 8) return;
    int gi = tid >> 3, o = tid & 7;
    float acc = bh[o];
    for (int k = 0; k < 128; ++k)
        acc = fmaf(g[gi * 128 + k], Wh[k * 8 + o], acc);
    out[tid] = acc;
}

// ---------------- Launch ----------------

extern "C" void kernel_launch(void* const* d_in, const int* in_sizes, int n_in,
                              void* d_out, int out_size, void* d_ws, size_t ws_size,
                              hipStream_t stream) {
    const float* x  = (const float*)d_in[0];
    const float* W1 = (const float*)d_in[1];
    const float* b1 = (const float*)d_in[2];
    const float* W2 = (const float*)d_in[3];
    const float* b2 = (const float*)d_in[4];
    const float* W3 = (const float*)d_in[5];
    const float* b3 = (const float*)d_in[6];
    const float* Wh = (const float*)d_in[7];
    const float* bh = (const float*)d_in[8];
    const int* edge_index = (const int*)d_in[9];
    const int* batch = (const int*)d_in[10];
    (void)n_in; (void)ws_size;

    const int N = in_sizes[10];
    const int E = in_sizes[9] / 2;
    const int G = out_size / 8;
    const int* esrc = edge_index;
    const int* edst = edge_index + E;

    size_t off = 0;
    auto take = [&](size_t bytes) {
        void* p = (char*)d_ws + off;
        off += (bytes + 255) & ~(size_t)255;
        return p;
    };
    int*   deg      = (int*)take((size_t)N * 4);
    float* dinv     = (float*)take((size_t)N * 4);
    int*   row_ptr  = (int*)take((size_t)(N + 1) * 4);
    u16*   rank     = (u16*)take((size_t)E * 2);
    u16*   csr_src  = (u16*)take((size_t)(E + N + 64) * 2);   // +64 pad: prefetch overread
    int*   bsum     = (int*)take(256 * 4);
    int*   boff     = (int*)take(256 * 4);
    float* part     = (float*)take((size_t)G * PSPLIT * 128 * 4);
    float* gpool    = (float*)take((size_t)G * 128 * 4);
    u16*   x16      = (u16*)take((size_t)N * 64 * 2);
    u16*   h16a     = (u16*)take((size_t)N * 128 * 2);
    u16*   h16b     = (u16*)take((size_t)N * 128 * 2);
    u16*   Wt1      = (u16*)take((size_t)128 * 64 * 2);
    u16*   Wt2      = (u16*)take((size_t)128 * 128 * 2);
    u16*   Wt3      = (u16*)take((size_t)128 * 128 * 2);
    float* bufA     = (float*)take((size_t)N * 128 * 4);

    int nblk = (N + 255) / 256;
    int fgrid = (N + 15) / 16;

    hipMemsetAsync(deg, 0, (size_t)N * 4, stream);

    deg_kernel<<<(E + 255) / 256, 256, 0, stream>>>(edst, deg, rank, E);
    scan_blocksum<<<nblk, 256, 0, stream>>>(deg, bsum, dinv, N);
    scan_offsets<<<1, 256, 0, stream>>>(bsum, boff, nblk);
    scan_rowptr<<<nblk, 256, 0, stream>>>(deg, boff, row_ptr, N);
    fill_kernel<<<(E + N + 255) / 256, 256, 0, stream>>>(esrc, edst, rank, row_ptr, csr_src, E, N);
    x2bf_kernel<<<(N * 64 / 8 + 255) / 256, 256, 0, stream>>>(x, dinv, (unsigned*)x16, N * 64 / 8);
    wt_all<<<(40960 + 255) / 256, 256, 0, stream>>>(W1, W2, W3, Wt1, Wt2, Wt3);

    // Fused layers (Agg(x)@W == Agg(x@W) used at layer 1)
    agg_gemm<64,  true,  true ><<<fgrid, 256, 0, stream>>>(x16,  Wt1, b1, h16a, row_ptr, csr_src, dinv, N);
    agg_gemm<128, true,  true ><<<fgrid, 256, 0, stream>>>(h16a, Wt2, b2, h16b, row_ptr, csr_src, dinv, N);
    agg_gemm<128, false, false><<<fgrid, 256, 0, stream>>>(h16b, Wt3, b3, bufA, row_ptr, csr_src, dinv, N);

    // Pool (binary-searched ranges) + head
    pool_part<<<G * PSPLIT, 256, 0, stream>>>(bufA, batch, part, N);
    pool_final<<<G, 128, 0, stream>>>(part, batch, gpool, N);
    head_kernel<<<(G * 8 + 255) / 256, 256, 0, stream>>>(gpool, Wh, bh, (float*)d_out, G);
}